// Round 3
// baseline (379.944 us; speedup 1.0000x reference)
//
#include <hip/hip_runtime.h>
#include <math.h>

// Problem constants: B=256, LMAX=512, NCOND=300, NHID=600
#define BB     256
#define LMAX   512
#define NCOND  300
#define NHID   600
#define NSEG   8          // 8 segments of 64 tokens
#define CHUNK  64
#define KPAD   320        // K padded to 10 chunks of 32 (k>=300 REAL zeros in ctx16/W1T)
#define KLDS   328        // fallback-path LDS row stride
#define NKC    10         // KPAD/32
#define SEGB   (CHUNK * KPAD * 2)   // bytes per ctx16 segment = 40,960

#define AS1 __attribute__((address_space(1)))
#define AS3 __attribute__((address_space(3)))

typedef short s16x8 __attribute__((ext_vector_type(8)));  // MFMA A/B frag (8 bf16)
typedef float f32x4 __attribute__((ext_vector_type(4)));  // MFMA accumulator
typedef unsigned short u16x8 __attribute__((ext_vector_type(8)));

// fp32 -> bf16 round-to-nearest-even
__device__ inline unsigned short f2bf(float f) {
    unsigned int x = __float_as_uint(f);
    x += 0x7fffu + ((x >> 16) & 1u);
    return (unsigned short)(x >> 16);
}

// ---------------------------------------------------------------------------
// k0: build W1T bf16 in FRAGMENT-MAJOR layout:
//   w1t[((ntile*NKC + kc)*64 + lane)*8 + j] = W1[kc*32+(lane>>4)*8+j][ntile*16+(lane&15)]
// -> a wave's B-frag load is one contiguous 1 KB global_load_dwordx4.
// ---------------------------------------------------------------------------
__global__ __launch_bounds__(256) void k0_w1t(const float* __restrict__ W1,
                                              unsigned short* __restrict__ w1t)
{
    const int t     = blockIdx.x * 256 + threadIdx.x;  // 0..25599
    const int lane  = t & 63;
    const int g     = t >> 6;                          // ntile*NKC + kc
    const int ntile = g / NKC;
    const int kc    = g - ntile * NKC;
    const int n     = ntile * 16 + (lane & 15);
    const int kbase = kc * 32 + (lane >> 4) * 8;
    union { unsigned short us[8]; s16x8 v8; } u;
#pragma unroll
    for (int j = 0; j < 8; ++j) {
        const int k = kbase + j;
        const float w = (n < NHID && k < NCOND) ? W1[(size_t)k * NHID + n] : 0.f;
        u.us[j] = f2bf(w);
    }
    *(s16x8*)(w1t + (size_t)t * 8) = u.v8;
}

// ---------------------------------------------------------------------------
// k0b: pre-convert ctx (fp32) -> ctx16 (bf16), live segments only.
//   Row layout: KPAD=320 elems/row; k in [300,320) = REAL zeros. Byte layout
//   within a 40,960 B segment is PRE-SWIZZLED: off' = (row*640+kbyte)^((row&7)<<4)
//   so k1's LINEAR global_load_lds DMA lands the tile swizzled in LDS
//   (rule #21; validated end-to-end in round 2).
//   16B output chunks: 2560 per segment / 256 threads = 10 iters exact.
//   XOR flips bits 4-6 only and chunk base is 16B-aligned -> alignment kept.
// ---------------------------------------------------------------------------
__global__ __launch_bounds__(256) void k0b_cvt(const float* __restrict__ ctx,
                                               const int* __restrict__ lengths,
                                               unsigned short* __restrict__ ctx16)
{
    const int b = blockIdx.x, s = blockIdx.y, tid = threadIdx.x;
    int count = lengths[b]; if (count < 1) count = 1;
    if (s * CHUNK >= count) return;                    // dead segment: k1 never reads it

    const float* src = ctx + ((size_t)b * LMAX + s * CHUNK) * NCOND;
    char* dst = (char*)(ctx16 + ((size_t)b * LMAX + s * CHUNK) * KPAD);

#pragma unroll
    for (int i = 0; i < 10; ++i) {
        const int c   = i * 256 + tid;      // 0..2559 (16B output chunk index)
        const int row = c / 40;             // 0..63
        const int q2  = c - row * 40;       // 0..39 (8-elem group; k = q2*8)
        float4 v0 = make_float4(0.f, 0.f, 0.f, 0.f);
        float4 v1 = make_float4(0.f, 0.f, 0.f, 0.f);
        const float* rsrc = src + (size_t)row * NCOND + q2 * 8;
        if (q2 < 38) v0 = *(const float4*)rsrc;          // k .. k+3 <= 299
        if (q2 < 37) v1 = *(const float4*)(rsrc + 4);    // k+4 .. k+7 <= 295+..
        union { unsigned short us[8]; u16x8 v8; } o;
        o.us[0] = f2bf(v0.x); o.us[1] = f2bf(v0.y);
        o.us[2] = f2bf(v0.z); o.us[3] = f2bf(v0.w);
        o.us[4] = f2bf(v1.x); o.us[5] = f2bf(v1.y);
        o.us[6] = f2bf(v1.z); o.us[7] = f2bf(v1.w);
        const int off = (row * 640 + q2 * 16) ^ ((row & 7) << 4);
        *(u16x8*)(dst + off) = o.v8;
    }
}

// ---------------------------------------------------------------------------
// k1_persist: grid (BB) x 512 threads (8 waves). ONE block per batch, looping
//   over its live segments with a 2-phase DMA pipeline (T3 minimum recipe):
//     prologue: STAGE(buf0, s=0); __syncthreads();
//     loop s:   STAGE(buf^1, s+1)   <- fire-and-forget, lands during compute
//               MFMA(buf[cur]) + epilogue accumulate (relu+rowmask -> ssum)
//               __syncthreads()     <- vmcnt(0) drain AFTER ~2000cy of MFMA
//   ch folded: 8 waves cover all 40 n-tiles -> A staged ONCE (was twice).
//   partial becomes [B][NHID] (one write per col per batch; 8x less traffic).
//   LDS: 2 x 40,960 = 81,920 B double buffer -> 1 block/CU, all 256 resident.
// ---------------------------------------------------------------------------
__global__ __launch_bounds__(512, 2) void k1_persist(
    const unsigned short* __restrict__ ctx16, const int* __restrict__ lengths,
    const unsigned short* __restrict__ w1t, const float* __restrict__ b1,
    float* __restrict__ partial)
{
    const int b = blockIdx.x;
    int count = lengths[b]; if (count < 1) count = 1;   // reference clamps lens >= 1
    const int nseg = (count + CHUNK - 1) >> 6;          // 1..8

    const int tid  = threadIdx.x;
    const int lane = tid & 63;
    const int wv   = tid >> 6;          // 0..7: wave owns n-tiles [wv*5, wv*5+5)
    const int ln15 = lane & 15;
    const int kg   = lane >> 4;

    __shared__ __align__(16) unsigned short atile[2][CHUNK * KPAD];  // 81,920 B

    // b1 slice in registers (per-lane, 5 cols)
    float bq[5];
#pragma unroll
    for (int nt = 0; nt < 5; ++nt) {
        const int colg = wv * 80 + nt * 16 + ln15;
        bq[nt] = (colg < NHID) ? b1[colg] : 0.f;
    }

    const unsigned short* bbase = w1t + ((size_t)(wv * 5) * NKC * 64 + lane) * 8;
    const char* gseg = (const char*)(ctx16 + (size_t)b * LMAX * KPAD);

    // ---- stage segment 0 into buf0 (5 DMA issues per wave; 40 KiB total)
#pragma unroll
    for (int r = 0; r < 5; ++r) {
        const int off = (r * 8 + wv) * 1024;
        __builtin_amdgcn_global_load_lds(
            (const AS1 void*)(gseg + off + lane * 16),
            (AS3 void*)((char*)atile[0] + off), 16, 0, 0);
    }

    float ssum[5] = {0.f, 0.f, 0.f, 0.f, 0.f};
    const int swz   = (ln15 & 7) << 4;
    const int abase = ln15 * 640 + kg * 16;

    __syncthreads();                                    // drain seg-0 DMA + sync

    for (int s = 0; s < nseg; ++s) {
        const int cur = s & 1;

        // ---- prefetch next segment into the other buffer (safe: end-of-(s-1)
        //      barrier guarantees everyone finished reading buf[cur^1])
        if (s + 1 < nseg) {
            const char* gnext = gseg + (size_t)(s + 1) * SEGB;
#pragma unroll
            for (int r = 0; r < 5; ++r) {
                const int off = (r * 8 + wv) * 1024;
                __builtin_amdgcn_global_load_lds(
                    (const AS1 void*)(gnext + off + lane * 16),
                    (AS3 void*)((char*)atile[cur ^ 1] + off), 16, 0, 0);
            }
        }

        // ---- MFMA over this segment (A from LDS w/ swizzle, B from L2-hot w1t)
        const char* ab = (const char*)atile[cur];

        f32x4 acc[5][4];
#pragma unroll
        for (int nt = 0; nt < 5; ++nt)
#pragma unroll
            for (int mt = 0; mt < 4; ++mt) acc[nt][mt] = (f32x4){0.f, 0.f, 0.f, 0.f};

        s16x8 bf[2][5];
#pragma unroll
        for (int nt = 0; nt < 5; ++nt) bf[0][nt] = *(const s16x8*)(bbase + nt * 5120);

#pragma unroll
        for (int kc = 0; kc < NKC; ++kc) {
            const int curk = kc & 1, nxtk = curk ^ 1;
            if (kc < NKC - 1) {
#pragma unroll
                for (int nt = 0; nt < 5; ++nt)
                    bf[nxtk][nt] = *(const s16x8*)(bbase + nt * 5120 + (kc + 1) * 512);
            }
            s16x8 af[4];
#pragma unroll
            for (int mt = 0; mt < 4; ++mt)
                af[mt] = *(const s16x8*)(ab + ((abase + mt * 10240 + kc * 64) ^ swz));
#pragma unroll
            for (int nt = 0; nt < 5; ++nt)
#pragma unroll
                for (int mt = 0; mt < 4; ++mt)
                    acc[nt][mt] = __builtin_amdgcn_mfma_f32_16x16x32_bf16(
                        af[mt], bf[curk][nt], acc[nt][mt], 0, 0, 0);
        }

        // ---- per-segment epilogue: bias + ReLU, mask rows >= valid, accumulate
        const int valid = min(count - s * CHUNK, CHUNK);
#pragma unroll
        for (int nt = 0; nt < 5; ++nt) {
            float t = 0.f;
#pragma unroll
            for (int mt = 0; mt < 4; ++mt) {
                const int rbase = mt * 16 + kg * 4;
#pragma unroll
                for (int r = 0; r < 4; ++r) {
                    const float h = fmaxf(acc[nt][mt][r] + bq[nt], 0.f);
                    if (rbase + r < valid) t += h;
                }
            }
            ssum[nt] += t;
        }

        __syncthreads();   // drains s+1 prefetch (landed during MFMA) + syncs buffers
    }

    // ---- final cross-lane reduce + single write per column
#pragma unroll
    for (int nt = 0; nt < 5; ++nt) {
        float v = ssum[nt];
        v += __shfl_xor(v, 16, 64);
        v += __shfl_xor(v, 32, 64);
        const int colg = wv * 80 + nt * 16 + ln15;
        if (kg == 0 && colg < NHID)
            partial[(size_t)b * NHID + colg] = v;
    }
}

// ---------------------------------------------------------------------------
// k2_gate2: new partial layout [B][NHID] (no sp loop). 2 batches per block
//   (same-n lanes share Wa loads); /len, gate = sigmoid(pooled@Wa + ba),
//   out = gate * x.
// ---------------------------------------------------------------------------
__global__ __launch_bounds__(640) void k2_gate2(
    const float* __restrict__ x, const int* __restrict__ lengths,
    const float* __restrict__ partial, const float* __restrict__ Wa,
    const float* __restrict__ ba, float* __restrict__ out)
{
    const int b0  = blockIdx.x * 2;
    const int tid = threadIdx.x;

    __shared__ float pl[2][NHID];

    if (tid < NHID) {
#pragma unroll
        for (int bb = 0; bb < 2; ++bb) {
            int count = lengths[b0 + bb]; if (count < 1) count = 1;
            pl[bb][tid] = partial[(size_t)(b0 + bb) * NHID + tid] / (float)count;
        }
    }
    __syncthreads();

    if (tid < 2 * NCOND) {
        const int bb = tid / NCOND;        // 0 or 1
        const int n  = tid - bb * NCOND;   // lanes 0..299 and 300..599 share Wa addrs
        const int b  = b0 + bb;
        float a0 = ba[n], a1 = 0.f, a2 = 0.f, a3 = 0.f;
        const float4* p4 = (const float4*)pl[bb];
        for (int h4 = 0; h4 < 148; h4 += 4) {   // h = 0..591
            const float4 pv0 = p4[h4];
            const float4 pv1 = p4[h4 + 1];
            const float4 pv2 = p4[h4 + 2];
            const float4 pv3 = p4[h4 + 3];
            const int hb = h4 * 4;
            a0 = fmaf(pv0.x, Wa[(size_t)(hb +  0) * NCOND + n], a0);
            a0 = fmaf(pv0.y, Wa[(size_t)(hb +  1) * NCOND + n], a0);
            a0 = fmaf(pv0.z, Wa[(size_t)(hb +  2) * NCOND + n], a0);
            a0 = fmaf(pv0.w, Wa[(size_t)(hb +  3) * NCOND + n], a0);
            a1 = fmaf(pv1.x, Wa[(size_t)(hb +  4) * NCOND + n], a1);
            a1 = fmaf(pv1.y, Wa[(size_t)(hb +  5) * NCOND + n], a1);
            a1 = fmaf(pv1.z, Wa[(size_t)(hb +  6) * NCOND + n], a1);
            a1 = fmaf(pv1.w, Wa[(size_t)(hb +  7) * NCOND + n], a1);
            a2 = fmaf(pv2.x, Wa[(size_t)(hb +  8) * NCOND + n], a2);
            a2 = fmaf(pv2.y, Wa[(size_t)(hb +  9) * NCOND + n], a2);
            a2 = fmaf(pv2.z, Wa[(size_t)(hb + 10) * NCOND + n], a2);
            a2 = fmaf(pv2.w, Wa[(size_t)(hb + 11) * NCOND + n], a2);
            a3 = fmaf(pv3.x, Wa[(size_t)(hb + 12) * NCOND + n], a3);
            a3 = fmaf(pv3.y, Wa[(size_t)(hb + 13) * NCOND + n], a3);
            a3 = fmaf(pv3.z, Wa[(size_t)(hb + 14) * NCOND + n], a3);
            a3 = fmaf(pv3.w, Wa[(size_t)(hb + 15) * NCOND + n], a3);
        }
        {   // tail: h = 592..599
            const float4 pv0 = p4[148];
            const float4 pv1 = p4[149];
            a0 = fmaf(pv0.x, Wa[(size_t)592 * NCOND + n], a0);
            a0 = fmaf(pv0.y, Wa[(size_t)593 * NCOND + n], a0);
            a0 = fmaf(pv0.z, Wa[(size_t)594 * NCOND + n], a0);
            a0 = fmaf(pv0.w, Wa[(size_t)595 * NCOND + n], a0);
            a1 = fmaf(pv1.x, Wa[(size_t)596 * NCOND + n], a1);
            a1 = fmaf(pv1.y, Wa[(size_t)597 * NCOND + n], a1);
            a1 = fmaf(pv1.z, Wa[(size_t)598 * NCOND + n], a1);
            a1 = fmaf(pv1.w, Wa[(size_t)599 * NCOND + n], a1);
        }
        const float acc  = (a0 + a1) + (a2 + a3);
        const float gate = 1.0f / (1.0f + expf(-acc));
        out[(size_t)b * NCOND + n] = gate * x[(size_t)b * NCOND + n];
    }
}

// ---------------------------------------------------------------------------
// Fallback path (ws too small for ctx16): exact round-0 kernels.
// ---------------------------------------------------------------------------
__global__ __launch_bounds__(256, 3) void k1_mfma_pool(
    const float* __restrict__ ctx, const int* __restrict__ lengths,
    const unsigned short* __restrict__ w1t, const float* __restrict__ b1,
    float* __restrict__ partial)
{
    const int b  = blockIdx.x;
    const int s  = blockIdx.y;
    const int ch = blockIdx.z;

    int count = lengths[b]; if (count < 1) count = 1;
    const int l0 = s * CHUNK;
    if (l0 >= count) return;
    const int valid = min(count - l0, CHUNK);

    const int tid  = threadIdx.x;
    const int lane = tid & 63;
    const int wv   = tid >> 6;
    const int ln15 = lane & 15;
    const int kg   = lane >> 4;

    __shared__ __align__(16) unsigned short atile[CHUNK * KLDS];

#pragma unroll
    for (int p = 0; p < 10; ++p) {
        const int i  = p * 256 + tid;
        const int r  = i / 40;
        const int c8 = i - r * 40;
        union { unsigned short us[8]; s16x8 v8; } u;
        if (r < valid && c8 < 38) {
            const float* src = ctx + ((size_t)b * LMAX + l0 + r) * NCOND + c8 * 8;
            const float4 v0 = *(const float4*)src;
            float4 v1 = make_float4(0.f, 0.f, 0.f, 0.f);
            if (c8 < 37) v1 = *(const float4*)(src + 4);
            u.us[0] = f2bf(v0.x); u.us[1] = f2bf(v0.y);
            u.us[2] = f2bf(v0.z); u.us[3] = f2bf(v0.w);
            u.us[4] = f2bf(v1.x); u.us[5] = f2bf(v1.y);
            u.us[6] = f2bf(v1.z); u.us[7] = f2bf(v1.w);
        } else {
#pragma unroll
            for (int j = 0; j < 8; ++j) u.us[j] = 0;
        }
        *(s16x8*)(atile + r * KLDS + c8 * 8) = u.v8;
    }
    __syncthreads();

    const int ntile0 = ch * 20 + wv * 5;
    const unsigned short* bbase = w1t + ((size_t)ntile0 * NKC * 64 + lane) * 8;
    const unsigned short* arow  = atile + ln15 * KLDS + kg * 8;

    f32x4 acc[5][4];
#pragma unroll
    for (int nt = 0; nt < 5; ++nt)
#pragma unroll
        for (int mt = 0; mt < 4; ++mt) acc[nt][mt] = (f32x4){0.f, 0.f, 0.f, 0.f};

    s16x8 bf[2][5];
#pragma unroll
    for (int nt = 0; nt < 5; ++nt) bf[0][nt] = *(const s16x8*)(bbase + nt * 5120);

#pragma unroll
    for (int kc = 0; kc < NKC; ++kc) {
        const int cur = kc & 1, nxt = cur ^ 1;
        if (kc < NKC - 1) {
#pragma unroll
            for (int nt = 0; nt < 5; ++nt)
                bf[nxt][nt] = *(const s16x8*)(bbase + nt * 5120 + (kc + 1) * 512);
        }
        s16x8 af[4];
#pragma unroll
        for (int mt = 0; mt < 4; ++mt)
            af[mt] = *(const s16x8*)(arow + mt * 16 * KLDS + kc * 32);
#pragma unroll
        for (int nt = 0; nt < 5; ++nt)
#pragma unroll
            for (int mt = 0; mt < 4; ++mt)
                acc[nt][mt] = __builtin_amdgcn_mfma_f32_16x16x32_bf16(
                    af[mt], bf[cur][nt], acc[nt][mt], 0, 0, 0);
    }

#pragma unroll
    for (int nt = 0; nt < 5; ++nt) {
        const int colg = ch * 320 + wv * 80 + nt * 16 + ln15;
        const float b1c = (colg < NHID) ? b1[colg] : 0.f;
        float ssum = 0.f;
#pragma unroll
        for (int mt = 0; mt < 4; ++mt) {
            const int rbase = mt * 16 + kg * 4;
#pragma unroll
            for (int r = 0; r < 4; ++r) {
                const float h = fmaxf(acc[nt][mt][r] + b1c, 0.f);
                if (rbase + r < valid) ssum += h;
            }
        }
        ssum += __shfl_xor(ssum, 16, 64);
        ssum += __shfl_xor(ssum, 32, 64);
        if (kg == 0 && colg < NHID)
            partial[((size_t)s * BB + b) * NHID + colg] = ssum;
    }
}

__global__ __launch_bounds__(640) void k2_gate(
    const float* __restrict__ x, const int* __restrict__ lengths,
    const float* __restrict__ partial, const float* __restrict__ Wa,
    const float* __restrict__ ba, float* __restrict__ out)
{
    const int b0  = blockIdx.x * 2;
    const int tid = threadIdx.x;

    __shared__ float pl[2][NHID];

    if (tid < NHID) {
#pragma unroll
        for (int bb = 0; bb < 2; ++bb) {
            int count = lengths[b0 + bb]; if (count < 1) count = 1;
            const int nch = (count + CHUNK - 1) >> 6;
            float ssum = 0.f;
            for (int sp = 0; sp < nch; ++sp)
                ssum += partial[((size_t)sp * BB + (b0 + bb)) * NHID + tid];
            pl[bb][tid] = ssum / (float)count;
        }
    }
    __syncthreads();

    if (tid < 2 * NCOND) {
        const int bb = tid / NCOND;
        const int n  = tid - bb * NCOND;
        const int b  = b0 + bb;
        float a0 = ba[n], a1 = 0.f, a2 = 0.f, a3 = 0.f;
        const float4* p4 = (const float4*)pl[bb];
        for (int h4 = 0; h4 < 148; h4 += 4) {
            const float4 pv0 = p4[h4];
            const float4 pv1 = p4[h4 + 1];
            const float4 pv2 = p4[h4 + 2];
            const float4 pv3 = p4[h4 + 3];
            const int hb = h4 * 4;
            a0 = fmaf(pv0.x, Wa[(size_t)(hb +  0) * NCOND + n], a0);
            a0 = fmaf(pv0.y, Wa[(size_t)(hb +  1) * NCOND + n], a0);
            a0 = fmaf(pv0.z, Wa[(size_t)(hb +  2) * NCOND + n], a0);
            a0 = fmaf(pv0.w, Wa[(size_t)(hb +  3) * NCOND + n], a0);
            a1 = fmaf(pv1.x, Wa[(size_t)(hb +  4) * NCOND + n], a1);
            a1 = fmaf(pv1.y, Wa[(size_t)(hb +  5) * NCOND + n], a1);
            a1 = fmaf(pv1.z, Wa[(size_t)(hb +  6) * NCOND + n], a1);
            a1 = fmaf(pv1.w, Wa[(size_t)(hb +  7) * NCOND + n], a1);
            a2 = fmaf(pv2.x, Wa[(size_t)(hb +  8) * NCOND + n], a2);
            a2 = fmaf(pv2.y, Wa[(size_t)(hb +  9) * NCOND + n], a2);
            a2 = fmaf(pv2.z, Wa[(size_t)(hb + 10) * NCOND + n], a2);
            a2 = fmaf(pv2.w, Wa[(size_t)(hb + 11) * NCOND + n], a2);
            a3 = fmaf(pv3.x, Wa[(size_t)(hb + 12) * NCOND + n], a3);
            a3 = fmaf(pv3.y, Wa[(size_t)(hb + 13) * NCOND + n], a3);
            a3 = fmaf(pv3.z, Wa[(size_t)(hb + 14) * NCOND + n], a3);
            a3 = fmaf(pv3.w, Wa[(size_t)(hb + 15) * NCOND + n], a3);
        }
        {
            const float4 pv0 = p4[148];
            const float4 pv1 = p4[149];
            a0 = fmaf(pv0.x, Wa[(size_t)592 * NCOND + n], a0);
            a0 = fmaf(pv0.y, Wa[(size_t)593 * NCOND + n], a0);
            a0 = fmaf(pv0.z, Wa[(size_t)594 * NCOND + n], a0);
            a0 = fmaf(pv0.w, Wa[(size_t)595 * NCOND + n], a0);
            a1 = fmaf(pv1.x, Wa[(size_t)596 * NCOND + n], a1);
            a1 = fmaf(pv1.y, Wa[(size_t)597 * NCOND + n], a1);
            a1 = fmaf(pv1.z, Wa[(size_t)598 * NCOND + n], a1);
            a1 = fmaf(pv1.w, Wa[(size_t)599 * NCOND + n], a1);
        }
        const float acc  = (a0 + a1) + (a2 + a3);
        const float gate = 1.0f / (1.0f + expf(-acc));
        out[(size_t)b * NCOND + n] = gate * x[(size_t)b * NCOND + n];
    }
}

extern "C" void kernel_launch(void* const* d_in, const int* in_sizes, int n_in,
                              void* d_out, int out_size, void* d_ws, size_t ws_size,
                              hipStream_t stream)
{
    // setup_inputs() order: x, context, lengths, W1, b1, Wa, ba
    const float* x       = (const float*)d_in[0];
    const float* ctx     = (const float*)d_in[1];
    const int*   lengths = (const int*)  d_in[2];
    const float* W1      = (const float*)d_in[3];
    const float* b1      = (const float*)d_in[4];
    const float* Wa      = (const float*)d_in[5];
    const float* ba      = (const float*)d_in[6];
    float*       out     = (float*)d_out;

    // fast-path ws layout: [w1t 409,600][partial 614,400][ctx16 83,886,080]
    const size_t W1T_B   = 409600;
    const size_t PART_B  = 614400;                          // [256][600] f32
    const size_t CTX16_B = (size_t)BB * LMAX * KPAD * 2;    // 83,886,080
    const size_t NEED    = W1T_B + PART_B + CTX16_B;

    unsigned short* w1t     = (unsigned short*)d_ws;
    float*          partial = (float*)((char*)d_ws + W1T_B);

    k0_w1t<<<100, 256, 0, stream>>>(W1, w1t);

    if (ws_size >= NEED) {
        unsigned short* ctx16 = (unsigned short*)((char*)d_ws + W1T_B + PART_B);
        k0b_cvt<<<dim3(BB, NSEG), 256, 0, stream>>>(ctx, lengths, ctx16);
        k1_persist<<<BB, 512, 0, stream>>>(ctx16, lengths, w1t, b1, partial);
        k2_gate2<<<BB / 2, 640, 0, stream>>>(x, lengths, partial, Wa, ba, out);
    } else {
        // fallback: exact round-0 path (partial = [8][256][600] at same base)
        k1_mfma_pool<<<dim3(BB, NSEG, 2), 256, 0, stream>>>(ctx, lengths, w1t, b1, partial);
        k2_gate<<<BB / 2, 640, 0, stream>>>(x, lengths, partial, Wa, ba, out);
    }
}